// Round 7
// baseline (90.379 us; speedup 1.0000x reference)
//
#include <hip/hip_runtime.h>
#include <math.h>

#define B_TOTAL 2048
#define I_TOTAL 2048
#define O_TOTAL 2048
#define KW 64
#define NIN 6
#define BLOCK 256
#define TILE_B 16              // b-rows per block (8 chunk-pairs)
#define CH 2                   // rows per LDS buffer (double-buffered)
#define NCHUNK (TILE_B / CH)   // 8
#define BBLOCKS (B_TOTAL / TILE_B)  /* 128 */
#define OBLOCKS (O_TOTAL / BLOCK)   /* 8   */

// ---------------------------------------------------------------------------
// v7: ONE fused kernel, ZERO workspace.
//   Rationale (rounds 0-6): four structurally different mains (naive staging,
//   async dbuf, 4x-less-traffic sweep, XCD-temporal swizzle) all land at
//   85-89us total; v5's direct counters showed every pipe <25% busy. The
//   remaining controllable costs are the prep dispatch + launch gap + the
//   wT/m32T workspace round-trip — so fuse everything:
//    * each thread owns one o and computes its OWN 64 sigmoid weights from
//      its contiguous table row (no transpose kernel; strided-lane reads are
//      L2-hot and issued once per block, hidden under the chunk-0 x DMA)
//    * mapping read directly (int64/int32 autodetect), 6 loads/thread
//    * x staging + fma tree verbatim from v2 (best-measured structure)
//   Also tests whether the 44us workspace re-poison fill is usage-conditional
//   (d_ws untouched here).
// ---------------------------------------------------------------------------
__device__ __forceinline__ void async_cp16(float* lds, const float* g)
{
    __builtin_amdgcn_global_load_lds(
        (const __attribute__((address_space(1))) void*)g,
        (__attribute__((address_space(3))) void*)lds,
        16, 0, 0);
}

__global__ __launch_bounds__(BLOCK, 3) void lut_fused(
    const float* __restrict__ x,
    const float* __restrict__ table,
    const unsigned int* __restrict__ map_raw,
    float* __restrict__ out)
{
    __shared__ float xs[2 * CH * I_TOTAL];   // 2 bufs x 2 rows x 8KB = 32 KB

    const int o    = blockIdx.y * BLOCK + threadIdx.x;
    const int b0   = blockIdx.x * TILE_B;
    const int wave = threadIdx.x >> 6;
    const int lane = threadIdx.x & 63;

    // --- issue chunk-0 DMA FIRST: weight/mapping setup hides its latency --
    {
        const float* src = x + (size_t)b0 * I_TOTAL;
        #pragma unroll
        for (int ti = 0; ti < 4; ++ti) {
            int off = (wave * 4 + ti) * 256;         // wave-uniform float off
            async_cp16(&xs[off], src + off + lane * 4);
        }
    }

    // --- mapping: int64 little-endian with values<2048 => odd words all 0 -
    const bool is64 = ((map_raw[1] | map_raw[3] | map_raw[5] | map_raw[7]) == 0u);
    int m[NIN];
    #pragma unroll
    for (int i = 0; i < NIN; ++i) {
        int idx = o * NIN + i;
        m[i] = is64 ? (int)map_raw[2 * idx] : (int)map_raw[idx];
    }

    // --- weights: sigmoid of this thread's own contiguous table row -------
    //   ww[k]    = sigmoid(table[o][k])                 k in [0,32)
    //   ww[k]    = sig(table[o][k]) - sig(table[o][k-32]) k in [32,64)
    float ww[KW];
    const float4* tp = (const float4*)(table + (size_t)o * KW);
    #pragma unroll
    for (int j = 0; j < 16; ++j) {
        float4 v = tp[j];
        ww[4 * j + 0] = 1.0f / (1.0f + __expf(-v.x));
        ww[4 * j + 1] = 1.0f / (1.0f + __expf(-v.y));
        ww[4 * j + 2] = 1.0f / (1.0f + __expf(-v.z));
        ww[4 * j + 3] = 1.0f / (1.0f + __expf(-v.w));
    }
    #pragma unroll
    for (int k = 32; k < KW; ++k) ww[k] -= ww[k - 32];   // in-place: ww[k-32] still sig

    __syncthreads();   // drains own vmcnt(0) (chunk-0 DMA), then barrier

    #pragma unroll 2
    for (int cc = 0; cc < NCHUNK; ++cc) {
        const int buf = cc & 1;

        // issue DMA for next chunk into the other buffer
        if (cc + 1 < NCHUNK) {
            const float* src = x + (size_t)(b0 + (cc + 1) * CH) * I_TOTAL;
            float* dst = &xs[(buf ^ 1) * CH * I_TOTAL];
            #pragma unroll
            for (int ti = 0; ti < 4; ++ti) {
                int off = (wave * 4 + ti) * 256;
                async_cp16(dst + off, src + off + lane * 4);
            }
        }

        #pragma unroll
        for (int cr = 0; cr < CH; ++cr) {
            const int rowc = (buf * CH + cr) * I_TOTAL;   // compile-time
            float xv[NIN];
            #pragma unroll
            for (int i = 0; i < NIN; ++i) xv[i] = xs[rowc + m[i]];  // LDS gather

            // multilinear contraction; level 0 uses precomputed lo/diff
            float tt[32];
            #pragma unroll
            for (int j = 0; j < 32; ++j) tt[j] = fmaf(xv[5], ww[j + 32], ww[j]);
            #pragma unroll
            for (int j = 0; j < 16; ++j) tt[j] = fmaf(xv[4], tt[j + 16] - tt[j], tt[j]);
            #pragma unroll
            for (int j = 0; j < 8;  ++j) tt[j] = fmaf(xv[3], tt[j + 8]  - tt[j], tt[j]);
            #pragma unroll
            for (int j = 0; j < 4;  ++j) tt[j] = fmaf(xv[2], tt[j + 4]  - tt[j], tt[j]);
            #pragma unroll
            for (int j = 0; j < 2;  ++j) tt[j] = fmaf(xv[1], tt[j + 2]  - tt[j], tt[j]);
            float res = fmaf(xv[0], tt[1] - tt[0], tt[0]);

            out[(size_t)(b0 + cc * CH + cr) * O_TOTAL + o] = res;  // coalesced
        }

        __syncthreads();  // own DMA drained (vmcnt 0) + all waves done with buf
    }
}

extern "C" void kernel_launch(void* const* d_in, const int* in_sizes, int n_in,
                              void* d_out, int out_size, void* d_ws, size_t ws_size,
                              hipStream_t stream)
{
    const float*        x       = (const float*)d_in[0];
    const float*        table   = (const float*)d_in[1];
    const unsigned int* map_raw = (const unsigned int*)d_in[2];
    float* out = (float*)d_out;
    (void)d_ws; (void)ws_size;   // workspace intentionally unused

    dim3 grid(BBLOCKS, OBLOCKS);
    lut_fused<<<grid, dim3(BLOCK), 0, stream>>>(x, table, map_raw, out);
}